// Round 1
// baseline (206.259 us; speedup 1.0000x reference)
//
#include <hip/hip_runtime.h>

// KPConv pipeline v3 — fused aggregate+GEMM:
//   k0: x [50000,64] f32 -> xb bf16
//   k1: weights [15,64,128] f32 -> Wt [128][960] bf16 (transposed)
//   k2 (fused): per 16-point tile:
//       Phase A: per point, wf[k,c] = sum_h w(h,k)*x(h,c) via one
//                16x16x32 bf16 MFMA per 16-chan group, operands SWAPPED
//                (A = gathered x, B = w) so D gives lane-contiguous c ->
//                packed 8B LDS stores. wf tile lives in LDS only.
//       Phase B: out[16,128] = wf[16,960] x Wt^T, A from LDS (XOR-swizzled,
//                conflict-free b128 reads), B streamed from L2-resident Wt.
//   wf never touches HBM (saves 96MB write + 96MB read vs v2).

#define NPTS   50000
#define HNB    32
#define KPTS   15
#define CING   64
#define COUTG  128
#define KDIM   960
#define MSUP   50000
#define INV_EXT 13.888889f

#define PPB      16    // points per block (16 = MFMA M)
#define WF_PITCH 968   // u16 pitch per point-row: 484 dwords = 4 mod 32 -> row spread

typedef __attribute__((ext_vector_type(8))) short bf16x8;
typedef __attribute__((ext_vector_type(8))) unsigned short u16x8;
typedef __attribute__((ext_vector_type(4))) float f32x4;

static __device__ __forceinline__ unsigned short f2bf(float f) {
    unsigned int u = __float_as_uint(f);
    u += 0x7FFFu + ((u >> 16) & 1u);
    return (unsigned short)(u >> 16);
}

// ---------------- k0: x -> bf16 ----------------
__global__ __launch_bounds__(256) void kpconv_x2bf(const float* __restrict__ x,
                                                   unsigned short* __restrict__ xb) {
    int i = (blockIdx.x * 256 + threadIdx.x) * 8;
    if (i >= MSUP * CING) return;
    float4 a = *(const float4*)(x + i);
    float4 b = *(const float4*)(x + i + 4);
    u16x8 o;
    o[0] = f2bf(a.x); o[1] = f2bf(a.y); o[2] = f2bf(a.z); o[3] = f2bf(a.w);
    o[4] = f2bf(b.x); o[5] = f2bf(b.y); o[6] = f2bf(b.z); o[7] = f2bf(b.w);
    *(u16x8*)(xb + i) = o;
}

// ---------------- k1: weights transpose ----------------
__global__ void kpconv_wt(const float* __restrict__ wgt, unsigned short* __restrict__ Wt) {
    int kc = blockIdx.x;
    int o  = threadIdx.x;
    Wt[(size_t)o * KDIM + kc] = f2bf(wgt[(size_t)kc * COUTG + o]);
}

// ---------------- k2: fused aggregate + GEMM ----------------
// Block: 256 thr = 4 waves, 16 points. Grid 3125 (exact).
// Phase A (per wave, 4 points): agg MFMA with swapped operands:
//   A-frag = gathered x: lane (l15,quad), elem j -> x[nb(h=quad*8+j)][c0+l15]
//   B-frag = w:          lane l15 = k,   elem j -> w(h=quad*8+j, k)
//   D[m=quad*4+r][n=l15] = wf[k=l15][c = c0 + quad*4 + r]  (c contiguous in lane!)
// LDS wf store: element kd = k*64+c at row-byte (kd*2)^(((kd>>6)&7)<<4).
// Phase B (per wave, 32 output cols): 30 k-steps of {1 ds_read_b128 A,
//   2 global b16x8 B, 2 MFMA}, kd ascending (same summation order as v2).
__global__ __launch_bounds__(256, 4) void kpconv_fused(
    const float* __restrict__ q_pts, const float* __restrict__ s_pts,
    const int* __restrict__ inds, const unsigned short* __restrict__ xb,
    const float* __restrict__ kpts, const unsigned short* __restrict__ Wt,
    const float* __restrict__ bias, float* __restrict__ out)
{
    __shared__ float4 nb[PPB * HNB];                 // 8192 B
    __shared__ unsigned short wfs[PPB * WF_PITCH];   // 30976 B  (total 39.2KB -> 4 blk/CU)

    const int tid  = threadIdx.x;
    const int wav  = tid >> 6;
    const int lane = tid & 63;
    const int l15  = lane & 15;
    const int quad = lane >> 4;
    const int p0   = blockIdx.x * PPB;

    // ---- stage neighbor displacements (coalesced inds, L2-hot s_pts gather) ----
#pragma unroll
    for (int t = 0; t < 2; ++t) {
        int pid = t * 256 + tid;          // 0..511 = p*32 + h
        int p = pid >> 5, h = pid & 31;
        int n = p0 + p;
        int m = inds[n * HNB + h];
        float qx = q_pts[n * 3 + 0];
        float qy = q_pts[n * 3 + 1];
        float qz = q_pts[n * 3 + 2];
        nb[pid] = make_float4(s_pts[m * 3 + 0] - qx,
                              s_pts[m * 3 + 1] - qy,
                              s_pts[m * 3 + 2] - qz,
                              __int_as_float(m));
    }
    __syncthreads();

    // ---- Phase A: aggregate 4 points per wave into LDS wf tile ----
    const bool kvalid = (l15 < KPTS);
    const int  kidx   = kvalid ? l15 : 0;
    const float kx = kpts[kidx * 3 + 0];
    const float ky = kpts[kidx * 3 + 1];
    const float kz = kpts[kidx * 3 + 2];

#pragma unroll 1
    for (int pp = 0; pp < 4; ++pp) {
        const int p = wav * 4 + pp;
        bf16x8 af;
        const unsigned short* xr[8];
#pragma unroll
        for (int j = 0; j < 8; ++j) {
            float4 v = nb[p * HNB + quad * 8 + j];
            int m = __float_as_int(v.w);
            xr[j] = xb + (((size_t)m) << 6) + l15;
            float dx = v.x - kx, dy = v.y - ky, dz = v.z - kz;
            float d  = sqrtf(dx * dx + dy * dy + dz * dz);
            float w  = kvalid ? fmaxf(0.f, 1.f - d * INV_EXT) : 0.f;
            af[j] = (short)f2bf(w);
        }

        f32x4 acc[4];
#pragma unroll
        for (int nt = 0; nt < 4; ++nt) acc[nt] = (f32x4){0.f, 0.f, 0.f, 0.f};

#pragma unroll
        for (int nt = 0; nt < 4; ++nt) {
            bf16x8 bfr;
#pragma unroll
            for (int j = 0; j < 8; ++j) bfr[j] = (short)xr[j][nt * 16];
            // swapped operands: D[c_sub][k]
            acc[nt] = __builtin_amdgcn_mfma_f32_16x16x32_bf16(bfr, af, acc[nt], 0, 0, 0);
        }

        if (kvalid) {   // lane's k = l15; mask k==15
            char* rowp = (char*)wfs + p * (WF_PITCH * 2);
#pragma unroll
            for (int nt = 0; nt < 4; ++nt) {
                unsigned int lo = (unsigned)f2bf(acc[nt][0]) | ((unsigned)f2bf(acc[nt][1]) << 16);
                unsigned int hi = (unsigned)f2bf(acc[nt][2]) | ((unsigned)f2bf(acc[nt][3]) << 16);
                // element kd = l15*64 + nt*16 + quad*4 + r ; byte = kd*2 ^ ((k&7)<<4)
                const int off = (l15 * 128 + nt * 32 + quad * 8) ^ ((l15 & 7) << 4);
                *(uint2*)(rowp + off) = make_uint2(lo, hi);
            }
        }
    }
    __syncthreads();

    // ---- Phase B: out[16 pts][wav*32 .. wav*32+32) ----
    f32x4 oacc[2];
    oacc[0] = (f32x4){0.f, 0.f, 0.f, 0.f};
    oacc[1] = (f32x4){0.f, 0.f, 0.f, 0.f};
    const unsigned short* b0 = Wt + (size_t)(wav * 32 + l15) * KDIM + quad * 8;

#pragma unroll
    for (int s = 0; s < 30; ++s) {
        // A chunk: row = point = l15, kd0 = s*32 + quad*8, swizzle key = (kd0>>6)&7
        const int aoff = (s * 64 + quad * 16) ^ (((s >> 1) & 7) << 4);
        bf16x8 afr = *(const bf16x8*)((const char*)wfs + l15 * (WF_PITCH * 2) + aoff);
        bf16x8 w0 = *(const bf16x8*)(b0 + s * 32);
        bf16x8 w1 = *(const bf16x8*)(b0 + 16 * KDIM + s * 32);
        oacc[0] = __builtin_amdgcn_mfma_f32_16x16x32_bf16(afr, w0, oacc[0], 0, 0, 0);
        oacc[1] = __builtin_amdgcn_mfma_f32_16x16x32_bf16(afr, w1, oacc[1], 0, 0, 0);
    }

#pragma unroll
    for (int nf = 0; nf < 2; ++nf) {
        const int col = wav * 32 + nf * 16 + l15;
        const float bv = bias[col];
#pragma unroll
        for (int r = 0; r < 4; ++r) {
            const long row = (long)p0 + quad * 4 + r;   // always < 50000 (3125*16 exact)
            out[row * COUTG + col] = oacc[nf][r] + bv;
        }
    }
}

extern "C" void kernel_launch(void* const* d_in, const int* in_sizes, int n_in,
                              void* d_out, int out_size, void* d_ws, size_t ws_size,
                              hipStream_t stream) {
    const float* q_pts = (const float*)d_in[0];
    const float* s_pts = (const float*)d_in[1];
    const int*   inds  = (const int*)d_in[2];
    const float* x     = (const float*)d_in[3];
    const float* kpts  = (const float*)d_in[4];
    const float* wgt   = (const float*)d_in[5];
    const float* bias  = (const float*)d_in[6];
    float* out = (float*)d_out;

    // ws layout: xb [50000*64] bf16 | Wt [128*960] bf16   (wf eliminated)
    unsigned short* xb = (unsigned short*)d_ws;
    unsigned short* Wt = xb + (size_t)MSUP * CING;

    kpconv_x2bf<<<(MSUP * CING / 8 + 255) / 256, 256, 0, stream>>>(x, xb);
    kpconv_wt<<<KDIM, COUTG, 0, stream>>>(wgt, Wt);
    kpconv_fused<<<NPTS / PPB, 256, 0, stream>>>(q_pts, s_pts, inds, xb, kpts, Wt, bias, out);
}

// Round 2
// 204.068 us; speedup vs baseline: 1.0107x; 1.0107x over previous
//
#include <hip/hip_runtime.h>

// KPConv pipeline v4 — fused aggregate+GEMM, full-TLP:
//   k0: x [50000,64] f32 -> xb bf16
//   k1: weights [15,64,128] f32 -> Wt [128][960] bf16 (transposed)
//   k2 (fused): block = 1024 thr = 16 waves = 16 points.
//     Phase A: 1 wave = 1 point (v2-agg TLP restored: 50000 waves).
//              wf[k,c] via swapped-operand 16x16x32 MFMA -> packed 8B
//              LDS stores, swizzle key ((kd>>5)&7)<<4, pitch 968 u16
//              (121 16B-groups, odd -> conflict-free b128 reads).
//     Phase B: 16 waves = 8 col-groups x 2 K-halves, 15 MFMA steps each;
//              halves combined through an LDS reduce tile.
//   wf never touches HBM.

#define NPTS   50000
#define HNB    32
#define KPTS   15
#define CING   64
#define COUTG  128
#define KDIM   960
#define MSUP   50000
#define INV_EXT 13.888889f

#define PPB       16    // points per block (= MFMA M)
#define WF_PITCH  968   // u16 per point-row; 1936B = 121*16 (odd 16B groups)
#define RED_PITCH 17    // f32 pitch in reduce tile

typedef __attribute__((ext_vector_type(8))) short bf16x8;
typedef __attribute__((ext_vector_type(8))) unsigned short u16x8;
typedef __attribute__((ext_vector_type(4))) float f32x4;

static __device__ __forceinline__ unsigned short f2bf(float f) {
    unsigned int u = __float_as_uint(f);
    u += 0x7FFFu + ((u >> 16) & 1u);
    return (unsigned short)(u >> 16);
}

// ---------------- k0: x -> bf16 ----------------
__global__ __launch_bounds__(256) void kpconv_x2bf(const float* __restrict__ x,
                                                   unsigned short* __restrict__ xb) {
    int i = (blockIdx.x * 256 + threadIdx.x) * 8;
    if (i >= MSUP * CING) return;
    float4 a = *(const float4*)(x + i);
    float4 b = *(const float4*)(x + i + 4);
    u16x8 o;
    o[0] = f2bf(a.x); o[1] = f2bf(a.y); o[2] = f2bf(a.z); o[3] = f2bf(a.w);
    o[4] = f2bf(b.x); o[5] = f2bf(b.y); o[6] = f2bf(b.z); o[7] = f2bf(b.w);
    *(u16x8*)(xb + i) = o;
}

// ---------------- k1: weights transpose ----------------
__global__ void kpconv_wt(const float* __restrict__ wgt, unsigned short* __restrict__ Wt) {
    int kc = blockIdx.x;
    int o  = threadIdx.x;
    Wt[(size_t)o * KDIM + kc] = f2bf(wgt[(size_t)kc * COUTG + o]);
}

// ---------------- k2: fused aggregate + GEMM ----------------
// Phase A MFMA (swapped operands):
//   A-frag = gathered x: lane (l15,quad), elem j -> x[nb(h=quad*8+j)][nt*16+l15]
//   B-frag = w:          lane l15 = k,    elem j -> w(h=quad*8+j, k)
//   D[m=quad*4+r][n=l15] = wf[k=l15][c = nt*16 + quad*4 + r]  (c lane-contiguous)
// LDS wf element kd=k*64+c at row-byte (kd*2) ^ (((kd>>5)&7)<<4).
// Phase B: A-frag row = point = l15, kd0 = s*32 + quad*8; read key (s&7)<<4
//   (uniform per instr). B streamed from L2-resident Wt. s = kh*15 + i.
__global__ __launch_bounds__(1024, 8) void kpconv_fused(
    const float* __restrict__ q_pts, const float* __restrict__ s_pts,
    const int* __restrict__ inds, const unsigned short* __restrict__ xb,
    const float* __restrict__ kpts, const unsigned short* __restrict__ Wt,
    const float* __restrict__ bias, float* __restrict__ out)
{
    __shared__ float4 nb[PPB * HNB];                   // 8192 B
    __shared__ unsigned short wfs[PPB * WF_PITCH];     // 30976 B
    __shared__ float red[8 * 16 * RED_PITCH];          // 8704 B  (47.9 KB total)

    const int tid  = threadIdx.x;
    const int wav  = tid >> 6;        // 0..15
    const int lane = tid & 63;
    const int l15  = lane & 15;
    const int quad = lane >> 4;
    const int p0   = blockIdx.x * PPB;
    const int n    = p0 + wav;        // this wave's point

    // ---- stage this wave's 32 neighbor displacements ----
    if (lane < HNB) {
        int m = inds[n * HNB + lane];
        float qx = q_pts[n * 3 + 0];
        float qy = q_pts[n * 3 + 1];
        float qz = q_pts[n * 3 + 2];
        nb[wav * HNB + lane] = make_float4(s_pts[m * 3 + 0] - qx,
                                           s_pts[m * 3 + 1] - qy,
                                           s_pts[m * 3 + 2] - qz,
                                           __int_as_float(m));
    }
    __syncthreads();

    // ---- Phase A: aggregate 1 point per wave into LDS wf tile ----
    const bool kvalid = (l15 < KPTS);
    const int  kidx   = kvalid ? l15 : 0;
    const float kx = kpts[kidx * 3 + 0];
    const float ky = kpts[kidx * 3 + 1];
    const float kz = kpts[kidx * 3 + 2];

    bf16x8 af;
    int mrow[8];
#pragma unroll
    for (int j = 0; j < 8; ++j) {
        float4 v = nb[wav * HNB + quad * 8 + j];
        mrow[j] = __float_as_int(v.w);
        float dx = v.x - kx, dy = v.y - ky, dz = v.z - kz;
        float d  = sqrtf(dx * dx + dy * dy + dz * dz);
        float w  = kvalid ? fmaxf(0.f, 1.f - d * INV_EXT) : 0.f;
        af[j] = (short)f2bf(w);
    }

    f32x4 acc[4];
#pragma unroll
    for (int nt = 0; nt < 4; ++nt) acc[nt] = (f32x4){0.f, 0.f, 0.f, 0.f};

#pragma unroll
    for (int nt = 0; nt < 4; ++nt) {
        bf16x8 bfr;
#pragma unroll
        for (int j = 0; j < 8; ++j)
            bfr[j] = (short)xb[(((size_t)mrow[j]) << 6) + nt * 16 + l15];
        acc[nt] = __builtin_amdgcn_mfma_f32_16x16x32_bf16(bfr, af, acc[nt], 0, 0, 0);
    }

    if (kvalid) {   // lane's k = l15; k==15 unused (KDIM = 15*64)
        char* rowp = (char*)wfs + wav * (WF_PITCH * 2);
#pragma unroll
        for (int nt = 0; nt < 4; ++nt) {
            unsigned int lo = (unsigned)f2bf(acc[nt][0]) | ((unsigned)f2bf(acc[nt][1]) << 16);
            unsigned int hi = (unsigned)f2bf(acc[nt][2]) | ((unsigned)f2bf(acc[nt][3]) << 16);
            // kd = l15*64 + nt*16 + quad*4 + r ; key = ((kd>>5)&7) = (l15*2 + (nt>>1)) & 7
            const int off = (l15 * 128 + nt * 32 + quad * 8) ^ ((((l15 << 1) + (nt >> 1)) & 7) << 4);
            *(uint2*)(rowp + off) = make_uint2(lo, hi);
        }
    }
    __syncthreads();

    // ---- Phase B: wave -> (col-group, K-half) ----
    const int cg = wav & 7;          // 8 groups of 16 output cols
    const int kh = wav >> 3;         // K-half: s in [kh*15, kh*15+15)
    f32x4 oacc = (f32x4){0.f, 0.f, 0.f, 0.f};
    const unsigned short* b0 = Wt + (size_t)(cg * 16 + l15) * KDIM + quad * 8;

#pragma unroll
    for (int i = 0; i < 15; ++i) {
        const int s = kh * 15 + i;
        const int aoff = (s * 64 + quad * 16) ^ ((s & 7) << 4);
        bf16x8 afr = *(const bf16x8*)((const char*)wfs + l15 * (WF_PITCH * 2) + aoff);
        bf16x8 wfr = *(const bf16x8*)(b0 + s * 32);
        oacc = __builtin_amdgcn_mfma_f32_16x16x32_bf16(afr, wfr, oacc, 0, 0, 0);
    }

    // ---- combine K-halves via LDS, add bias, write out ----
    float* rp = red + cg * (16 * RED_PITCH);
    if (kh == 1) {
#pragma unroll
        for (int r = 0; r < 4; ++r)
            rp[(quad * 4 + r) * RED_PITCH + l15] = oacc[r];
    }
    __syncthreads();
    if (kh == 0) {
        const int col = cg * 16 + l15;
        const float bv = bias[col];
#pragma unroll
        for (int r = 0; r < 4; ++r) {
            const int row = p0 + quad * 4 + r;        // exact: 3125*16 = 50000
            out[(size_t)row * COUTG + col] = oacc[r] + rp[(quad * 4 + r) * RED_PITCH + l15] + bv;
        }
    }
}

extern "C" void kernel_launch(void* const* d_in, const int* in_sizes, int n_in,
                              void* d_out, int out_size, void* d_ws, size_t ws_size,
                              hipStream_t stream) {
    const float* q_pts = (const float*)d_in[0];
    const float* s_pts = (const float*)d_in[1];
    const int*   inds  = (const int*)d_in[2];
    const float* x     = (const float*)d_in[3];
    const float* kpts  = (const float*)d_in[4];
    const float* wgt   = (const float*)d_in[5];
    const float* bias  = (const float*)d_in[6];
    float* out = (float*)d_out;

    // ws layout: xb [50000*64] bf16 | Wt [128*960] bf16
    unsigned short* xb = (unsigned short*)d_ws;
    unsigned short* Wt = xb + (size_t)MSUP * CING;

    kpconv_x2bf<<<(MSUP * CING / 8 + 255) / 256, 256, 0, stream>>>(x, xb);
    kpconv_wt<<<KDIM, COUTG, 0, stream>>>(wgt, Wt);
    kpconv_fused<<<NPTS / PPB, 1024, 0, stream>>>(q_pts, s_pts, inds, xb, kpts, Wt, bias, out);
}